// Round 8
// baseline (198.484 us; speedup 1.0000x reference)
//
// Performer FAVOR+ on MI355X — R8: p1 with raw s_barrier (lgkm-only drain, no
// vmcnt drain), 2 barriers/tile, VT/ssq double-buffered, atomic-free partials
// staged in d_out + p1r reducer. Arithmetic identical to R7 (validated).
#include <hip/hip_runtime.h>

typedef short short8 __attribute__((ext_vector_type(8)));
typedef float f32x4 __attribute__((ext_vector_type(4)));

namespace {
constexpr int Sc = 8192, Dc = 64;
constexpr int NH = 64;                 // B*H heads
// p1 chunking
constexpr int CH1 = 512;               // rows per block -> grid 1024
constexpr int TPT1 = CH1 / 64;         // 8 tiles
constexpr int NCHUNK1 = Sc / CH1;      // 16
// p2 chunking
constexpr int CH2 = 1024;
constexpr int TPT2 = CH2 / 64;
constexpr int NCHUNK2 = Sc / CH2;
constexpr int PSTRIDE = 4160;          // per-chunk partial: 4096 B1 + 64 den
}

__device__ __forceinline__ void lds_barrier() {
  __builtin_amdgcn_sched_barrier(0);
  asm volatile("s_waitcnt lgkmcnt(0)" ::: "memory");
  __builtin_amdgcn_s_barrier();
  __builtin_amdgcn_sched_barrier(0);
}

__device__ __forceinline__ unsigned bf16rtne(float x) {
  unsigned u = __builtin_bit_cast(unsigned, x);
  return (u + 0x7fffu + ((u >> 16) & 1u)) >> 16;
}
__device__ __forceinline__ unsigned pk2bf(float x, float y) {
  return bf16rtne(x) | (bf16rtne(y) << 16);
}
__device__ __forceinline__ unsigned pkhl(float x) {
  unsigned u = __builtin_bit_cast(unsigned, x);
  unsigned rh = (u + 0x7fffu + ((u >> 16) & 1u)) & 0xffff0000u;
  float res = x - __builtin_bit_cast(float, rh);
  return (rh >> 16) | (__builtin_bit_cast(unsigned, res) & 0xffff0000u);
}
__device__ __forceinline__ void bsplit(float x, short& hi, short& lo) {
  unsigned p = pkhl(x);
  hi = (short)(p & 0xffff);
  lo = (short)(p >> 16);
}
__device__ __forceinline__ short8 exhi(uint4 q0, uint4 q1) {
  union { unsigned u[4]; short8 s; } r;
  r.u[0] = __builtin_amdgcn_perm(q0.y, q0.x, 0x05040100u);
  r.u[1] = __builtin_amdgcn_perm(q0.w, q0.z, 0x05040100u);
  r.u[2] = __builtin_amdgcn_perm(q1.y, q1.x, 0x05040100u);
  r.u[3] = __builtin_amdgcn_perm(q1.w, q1.z, 0x05040100u);
  return r.s;
}
__device__ __forceinline__ short8 exlo(uint4 q0, uint4 q1) {
  union { unsigned u[4]; short8 s; } r;
  r.u[0] = __builtin_amdgcn_perm(q0.y, q0.x, 0x07060302u);
  r.u[1] = __builtin_amdgcn_perm(q0.w, q0.z, 0x07060302u);
  r.u[2] = __builtin_amdgcn_perm(q1.y, q1.x, 0x07060302u);
  r.u[3] = __builtin_amdgcn_perm(q1.w, q1.z, 0x07060302u);
  return r.s;
}
__device__ __forceinline__ short8 exsel(uint4 q0, uint4 q1, unsigned sel) {
  union { unsigned u[4]; short8 s; } r;
  r.u[0] = __builtin_amdgcn_perm(q0.y, q0.x, sel);
  r.u[1] = __builtin_amdgcn_perm(q0.w, q0.z, sel);
  r.u[2] = __builtin_amdgcn_perm(q1.y, q1.x, sel);
  r.u[3] = __builtin_amdgcn_perm(q1.w, q1.z, sel);
  return r.s;
}

__global__ void p0(const float* __restrict__ omega, short* __restrict__ wT) {
  int i = blockIdx.x * 256 + threadIdx.x;
  if (i < 4096) {
    int m = i >> 6, d = i & 63;
    short hi, lo;
    bsplit(omega[d * 64 + m], hi, lo);
    wT[m * 64 + d] = hi;
    wT[4096 + m * 64 + d] = lo;
  }
}

// ---------------- Phase 1: per-chunk partials of B1[m][c] and den[m]
__global__ __launch_bounds__(256, 3) void p1(
    const float* __restrict__ Kg, const float* __restrict__ Vg,
    const short* __restrict__ wT, float* __restrict__ part) {
  __shared__ unsigned Kpk[64 * 68];     // K tile packed hi|lo, [row][d] (single)
  __shared__ unsigned PT[64 * 68];      // k'^T bf16 low16, [m][s] (single)
  __shared__ unsigned VT2[2][32 * 68];  // V^T bf16 c-pairs (double-buffered)
  __shared__ float ssq[2][64];          // row sumsq (double-buffered)

  const int t = threadIdx.x;
  const int lane = t & 63;
  const int w = t >> 6;      // wave 0..3
  const int a = lane & 15;
  const int g = lane >> 4;   // 0..3
  const int bh = blockIdx.x / NCHUNK1, ch = blockIdx.x % NCHUNK1;
  const float* Kb = Kg + ((size_t)bh * Sc + (size_t)ch * CH1) * Dc;
  const float* Vb = Vg + ((size_t)bh * Sc + (size_t)ch * CH1) * Dc;
  const unsigned vsel = (a & 1) ? 0x07060302u : 0x05040100u;

  // omega B-frags: lane holds w[d=32ks+8g+j][m=16mt+a]
  short8 wfh[4][2], wfl[4][2];
#pragma unroll
  for (int mt = 0; mt < 4; ++mt)
#pragma unroll
    for (int ks = 0; ks < 2; ++ks) {
      int off = (a + 16 * mt) * 64 + 32 * ks + 8 * g;
      wfh[mt][ks] = *(const short8*)(wT + off);
      wfl[mt][ks] = *(const short8*)(wT + 4096 + off);
    }

  float4 kreg[4], vreg[4];
  auto load_tile = [&](int tile) {
    const float4* Kt = (const float4*)(Kb + (size_t)tile * 64 * Dc);
    const float4* Vt = (const float4*)(Vb + (size_t)tile * 64 * Dc);
#pragma unroll
    for (int rr = 0; rr < 4; ++rr) {
      kreg[rr] = Kt[rr * 256 + t];
      vreg[rr] = Vt[rr * 256 + t];
    }
  };
  auto store_tile = [&](int buf) {
#pragma unroll
    for (int rr = 0; rr < 4; ++rr) {
      int idx = rr * 256 + t;
      int row = idx >> 4;   // 0..63
      int c4 = idx & 15;
      float4 kv = kreg[rr];
      uint4 kp;
      kp.x = pkhl(kv.x); kp.y = pkhl(kv.y);
      kp.z = pkhl(kv.z); kp.w = pkhl(kv.w);
      *(uint4*)&Kpk[row * 68 + 4 * c4] = kp;
      float ps = kv.x * kv.x + kv.y * kv.y + kv.z * kv.z + kv.w * kv.w;
      ps += __shfl_xor(ps, 1, 64); ps += __shfl_xor(ps, 2, 64);
      ps += __shfl_xor(ps, 4, 64); ps += __shfl_xor(ps, 8, 64);
      if (c4 == 0) ssq[buf][row] = ps;
      float4 vv = vreg[rr];
      int sw = row ^ (4 * ((c4 >> 1) & 7));
      VT2[buf][(2 * c4 + 0) * 68 + sw] = pk2bf(vv.x, vv.y);
      VT2[buf][(2 * c4 + 1) * 68 + sw] = pk2bf(vv.z, vv.w);
    }
  };

  f32x4 B1a[4];
#pragma unroll
  for (int ct = 0; ct < 4; ++ct) B1a[ct] = (f32x4){0.f, 0.f, 0.f, 0.f};
  float dpart[4] = {0.f, 0.f, 0.f, 0.f};

  load_tile(0);
  store_tile(0);
  lds_barrier();

  for (int tile = 0; tile < TPT1; ++tile) {
    const int cur = tile & 1;
    if (tile + 1 < TPT1) load_tile(tile + 1);  // in flight across barriers

    // GEMM1: X[s][m] = K @ omega (3-product split; feeds exp -> keep precise)
    f32x4 X[4];
#pragma unroll
    for (int mt = 0; mt < 4; ++mt) X[mt] = (f32x4){0.f, 0.f, 0.f, 0.f};
#pragma unroll
    for (int ks = 0; ks < 2; ++ks) {
      const unsigned* kb = &Kpk[(16 * w + a) * 68 + 32 * ks + 8 * g];
      uint4 q0 = *(const uint4*)kb;
      uint4 q1 = *(const uint4*)(kb + 4);
      short8 ah = exhi(q0, q1), al = exlo(q0, q1);
#pragma unroll
      for (int mt = 0; mt < 4; ++mt) {
        X[mt] = __builtin_amdgcn_mfma_f32_16x16x32_bf16(ah, wfh[mt][ks], X[mt], 0, 0, 0);
        X[mt] = __builtin_amdgcn_mfma_f32_16x16x32_bf16(ah, wfl[mt][ks], X[mt], 0, 0, 0);
        X[mt] = __builtin_amdgcn_mfma_f32_16x16x32_bf16(al, wfh[mt][ks], X[mt], 0, 0, 0);
      }
    }

    // exp -> k'; f32 for den, single bf16 (low16) for the P@V product
    float sq[4];
#pragma unroll
    for (int r = 0; r < 4; ++r) sq[r] = ssq[cur][16 * w + 4 * g + r];
#pragma unroll
    for (int mt = 0; mt < 4; ++mt) {
      uint4 pp;
      float p_;
      p_ = 0.125f * __expf(X[mt][0] - 0.5f * sq[0]); dpart[mt] += p_; pp.x = bf16rtne(p_);
      p_ = 0.125f * __expf(X[mt][1] - 0.5f * sq[1]); dpart[mt] += p_; pp.y = bf16rtne(p_);
      p_ = 0.125f * __expf(X[mt][2] - 0.5f * sq[2]); dpart[mt] += p_; pp.z = bf16rtne(p_);
      p_ = 0.125f * __expf(X[mt][3] - 0.5f * sq[3]); dpart[mt] += p_; pp.w = bf16rtne(p_);
      *(uint4*)&PT[(16 * mt + a) * 68 + 16 * w + 4 * g] = pp;
    }
    lds_barrier();  // A: PT visible; Kpk/ssq[cur] reads done

    // GEMM2: B1 += P^T @ V  (single bf16)
#pragma unroll
    for (int ks = 0; ks < 2; ++ks) {
      const unsigned* pb = &PT[(16 * w + a) * 68 + 32 * ks + 8 * g];
      uint4 r0 = *(const uint4*)pb;
      uint4 r1 = *(const uint4*)(pb + 4);
      short8 pah = exhi(r0, r1);
#pragma unroll
      for (int ct = 0; ct < 4; ++ct) {
        int c2 = 8 * ct + (a >> 1);
        int kk4 = 4 * ((2 * ct + (a >> 3)) & 7);
        int s0 = (32 * ks + 8 * g) ^ kk4;
        int s1 = (32 * ks + 8 * g + 4) ^ kk4;
        const unsigned* vb = &VT2[cur][c2 * 68];
        uint4 v0 = *(const uint4*)(vb + s0);
        uint4 v1 = *(const uint4*)(vb + s1);
        short8 vh = exsel(v0, v1, vsel);
        B1a[ct] = __builtin_amdgcn_mfma_f32_16x16x32_bf16(pah, vh, B1a[ct], 0, 0, 0);
      }
    }
    // stage next tile: Kpk (safe post-barA), VT2[nxt]/ssq[nxt] (other buffer)
    if (tile + 1 < TPT1) store_tile(cur ^ 1);
    lds_barrier();  // B: stores visible; PT/VT2[cur] reads done
  }

  // epilogue: plain coalesced partial stores (no atomics)
  float* pp = part + (size_t)blockIdx.x * PSTRIDE;
#pragma unroll
  for (int ct = 0; ct < 4; ++ct)
#pragma unroll
    for (int r = 0; r < 4; ++r)
      pp[(16 * w + 4 * g + r) * 64 + 16 * ct + a] = B1a[ct][r];

  // den partial: reduce over g in-wave, across waves via LDS (reuse PT)
  float* dredf = (float*)PT;
#pragma unroll
  for (int mt = 0; mt < 4; ++mt) {
    float v = dpart[mt];
    v += __shfl_xor(v, 16, 64);
    v += __shfl_xor(v, 32, 64);
    if (g == 0) dredf[w * 64 + mt * 16 + a] = v;
  }
  lds_barrier();
  if (t < 64) {
    float s = dredf[t] + dredf[64 + t] + dredf[128 + t] + dredf[192 + t];
    pp[4096 + t] = s;
  }
}

// ---------------- p1r: reduce NCHUNK1 partials -> b1, den
__global__ __launch_bounds__(256) void p1r(
    const float* __restrict__ part, float* __restrict__ b1,
    float* __restrict__ den) {
  int o = blockIdx.x * 256 + threadIdx.x;
  if (o >= NH * PSTRIDE) return;
  int bh = o / PSTRIDE, i = o % PSTRIDE;
  const float* p = part + (size_t)bh * NCHUNK1 * PSTRIDE + i;
  float s = 0.f;
#pragma unroll
  for (int c = 0; c < NCHUNK1; ++c) s += p[(size_t)c * PSTRIDE];
  if (i < 4096) b1[bh * 4096 + i] = s;
  else den[bh * 64 + (i - 4096)] = s;
}

// ---------------- Phase 2 (unchanged — at HBM roofline)
__global__ __launch_bounds__(256, 2) void p2(
    const float* __restrict__ Qg, const short* __restrict__ wT,
    const float* __restrict__ b1, const float* __restrict__ den,
    float* __restrict__ out) {
  __shared__ unsigned Qpk[64 * 68];
  __shared__ unsigned QP[64 * 68];
  __shared__ short B1h[64 * 72], B1l[64 * 72];
  __shared__ float denv[64];
  __shared__ float ssq[64];

  const int t = threadIdx.x;
  const int lane = t & 63;
  const int w = t >> 6;
  const int a = lane & 15;
  const int g = lane >> 4;
  const int bh = blockIdx.x / NCHUNK2, ch = blockIdx.x % NCHUNK2;
  const float* Qb = Qg + ((size_t)bh * Sc + (size_t)ch * CH2) * Dc;

  short8 wfh[4][2], wfl[4][2];
#pragma unroll
  for (int mt = 0; mt < 4; ++mt)
#pragma unroll
    for (int ks = 0; ks < 2; ++ks) {
      int off = (a + 16 * mt) * 64 + 32 * ks + 8 * g;
      wfh[mt][ks] = *(const short8*)(wT + off);
      wfl[mt][ks] = *(const short8*)(wT + 4096 + off);
    }

  const float* b1g = b1 + (size_t)bh * 4096;
  for (int i = t; i < 4096; i += 256) {
    int m = i >> 6, c = i & 63;
    short hi, lo;
    bsplit(b1g[i], hi, lo);
    B1h[c * 72 + m] = hi;
    B1l[c * 72 + m] = lo;
  }
  if (t < 64) denv[t] = den[bh * 64 + t];

  float4 qreg[4];
  auto load_tile = [&](int tile) {
    const float4* Qt = (const float4*)(Qb + (size_t)tile * 64 * Dc);
#pragma unroll
    for (int rr = 0; rr < 4; ++rr) qreg[rr] = Qt[rr * 256 + t];
  };
  auto store_tile = [&]() {
#pragma unroll
    for (int rr = 0; rr < 4; ++rr) {
      int idx = rr * 256 + t;
      int row = idx >> 4;
      int c4 = idx & 15;
      float4 kv = qreg[rr];
      uint4 qp;
      qp.x = pkhl(kv.x); qp.y = pkhl(kv.y);
      qp.z = pkhl(kv.z); qp.w = pkhl(kv.w);
      *(uint4*)&Qpk[row * 68 + 4 * c4] = qp;
      float ps = kv.x * kv.x + kv.y * kv.y + kv.z * kv.z + kv.w * kv.w;
      ps += __shfl_xor(ps, 1, 64); ps += __shfl_xor(ps, 2, 64);
      ps += __shfl_xor(ps, 4, 64); ps += __shfl_xor(ps, 8, 64);
      if (c4 == 0) ssq[row] = ps;
    }
  };

  load_tile(0);
  store_tile();
  __syncthreads();

  for (int tile = 0; tile < TPT2; ++tile) {
    if (tile + 1 < TPT2) load_tile(tile + 1);

    f32x4 X[4];
#pragma unroll
    for (int mt = 0; mt < 4; ++mt) X[mt] = (f32x4){0.f, 0.f, 0.f, 0.f};
#pragma unroll
    for (int ks = 0; ks < 2; ++ks) {
      const unsigned* qb = &Qpk[(16 * w + a) * 68 + 32 * ks + 8 * g];
      uint4 q0 = *(const uint4*)qb;
      uint4 q1 = *(const uint4*)(qb + 4);
      short8 ah = exhi(q0, q1), al = exlo(q0, q1);
#pragma unroll
      for (int mt = 0; mt < 4; ++mt) {
        X[mt] = __builtin_amdgcn_mfma_f32_16x16x32_bf16(ah, wfh[mt][ks], X[mt], 0, 0, 0);
        X[mt] = __builtin_amdgcn_mfma_f32_16x16x32_bf16(ah, wfl[mt][ks], X[mt], 0, 0, 0);
        X[mt] = __builtin_amdgcn_mfma_f32_16x16x32_bf16(al, wfh[mt][ks], X[mt], 0, 0, 0);
      }
    }

    float sq[4];
#pragma unroll
    for (int r = 0; r < 4; ++r) sq[r] = ssq[16 * w + 4 * g + r];
    float dv[4];
#pragma unroll
    for (int mt = 0; mt < 4; ++mt) dv[mt] = denv[16 * mt + a];
    float dn[4] = {0.f, 0.f, 0.f, 0.f};
#pragma unroll
    for (int mt = 0; mt < 4; ++mt) {
#pragma unroll
      for (int r = 0; r < 4; ++r) {
        float p_ = 0.125f * __expf(X[mt][r] - 0.5f * sq[r]);
        dn[r] = fmaf(p_, dv[mt], dn[r]);
        QP[(16 * w + 4 * g + r) * 68 + 16 * mt + a] = pkhl(p_);
      }
    }
#pragma unroll
    for (int r = 0; r < 4; ++r) {
      dn[r] += __shfl_xor(dn[r], 1, 64);
      dn[r] += __shfl_xor(dn[r], 2, 64);
      dn[r] += __shfl_xor(dn[r], 4, 64);
      dn[r] += __shfl_xor(dn[r], 8, 64);
    }
    __syncthreads();  // A

    f32x4 O[4];
#pragma unroll
    for (int ct = 0; ct < 4; ++ct) O[ct] = (f32x4){0.f, 0.f, 0.f, 0.f};
#pragma unroll
    for (int ks = 0; ks < 2; ++ks) {
      const unsigned* qb = &QP[(16 * w + a) * 68 + 32 * ks + 8 * g];
      uint4 r0 = *(const uint4*)qb;
      uint4 r1 = *(const uint4*)(qb + 4);
      short8 qh = exhi(r0, r1), ql = exlo(r0, r1);
#pragma unroll
      for (int ct = 0; ct < 4; ++ct) {
        short8 bh_ = *(const short8*)&B1h[(16 * ct + a) * 72 + 32 * ks + 8 * g];
        short8 bl_ = *(const short8*)&B1l[(16 * ct + a) * 72 + 32 * ks + 8 * g];
        O[ct] = __builtin_amdgcn_mfma_f32_16x16x32_bf16(qh, bh_, O[ct], 0, 0, 0);
        O[ct] = __builtin_amdgcn_mfma_f32_16x16x32_bf16(qh, bl_, O[ct], 0, 0, 0);
        O[ct] = __builtin_amdgcn_mfma_f32_16x16x32_bf16(ql, bh_, O[ct], 0, 0, 0);
      }
    }

    float inv[4];
#pragma unroll
    for (int r = 0; r < 4; ++r) inv[r] = 1.0f / dn[r];
    float* ob = out + ((size_t)bh * Sc + (size_t)ch * CH2 + tile * 64 + 16 * w + 4 * g) * 64;
#pragma unroll
    for (int ct = 0; ct < 4; ++ct)
#pragma unroll
      for (int r = 0; r < 4; ++r)
        ob[r * 64 + 16 * ct + a] = O[ct][r] * inv[r];
    __syncthreads();  // B
    if (tile + 1 < TPT2) store_tile();
    __syncthreads();  // C
  }
}

extern "C" void kernel_launch(void* const* d_in, const int* in_sizes, int n_in,
                              void* d_out, int out_size, void* d_ws, size_t ws_size,
                              hipStream_t stream) {
  const float* Q = (const float*)d_in[0];
  const float* K = (const float*)d_in[1];
  const float* V = (const float*)d_in[2];
  const float* omega = (const float*)d_in[3];
  float* outp = (float*)d_out;
  // partials live in d_out (dead space until p2 fully overwrites it)
  float* part = (float*)d_out;   // NH*NCHUNK1*PSTRIDE = 17 MB << 128 MB
  float* b1 = (float*)d_ws;                    // 64*4096 floats
  float* den = b1 + (size_t)NH * 4096;         // 64*64 floats
  short* wT = (short*)(den + NH * 64);         // 8192 shorts

  p0<<<16, 256, 0, stream>>>(omega, wT);
  p1<<<NH * NCHUNK1, 256, 0, stream>>>(K, V, wT, part);
  p1r<<<(NH * PSTRIDE + 255) / 256, 256, 0, stream>>>(part, b1, den);
  p2<<<NH * NCHUNK2, 256, 0, stream>>>(Q, wT, b1, den, outp);
}

// Round 9
// 156.818 us; speedup vs baseline: 1.2657x; 1.2657x over previous
//
// Performer FAVOR+ on MI355X — R9: p1 rebuilt barrier-free/LDS-free.
// Per-wave independent 256-row chunks; K/V loaded direct-to-register in MFMA
// fragment layout; GEMM1 (K@w, 16x16x32 3-product) D-frag chains directly into
// GEMM2 (P^T@V, 16x16x16 single-bf16) A-frag in registers. Partials -> d_out,
// p1r reduces. p2 unchanged (at HBM roofline).
#include <hip/hip_runtime.h>

typedef short short8 __attribute__((ext_vector_type(8)));
typedef short s4b __attribute__((ext_vector_type(4)));
typedef float f32x4 __attribute__((ext_vector_type(4)));

namespace {
constexpr int Sc = 8192, Dc = 64;
constexpr int NH = 64;             // B*H heads
constexpr int CROWS = 256;         // rows per wave (chunk)
constexpr int SLABS = CROWS / 16;  // 16 slabs of 16 rows
constexpr int NCH1 = Sc / CROWS;   // 32 chunks per head
constexpr int PSTRIDE = 4160;      // 4096 B1 + 64 den
// p2 chunking
constexpr int CH2 = 1024;
constexpr int TPT2 = CH2 / 64;
constexpr int NCHUNK2 = Sc / CH2;
}

__device__ __forceinline__ unsigned bf16rtne(float x) {
  unsigned u = __builtin_bit_cast(unsigned, x);
  return (u + 0x7fffu + ((u >> 16) & 1u)) >> 16;
}
__device__ __forceinline__ void bsplitu(float x, unsigned& hi, unsigned& lo) {
  unsigned u = __builtin_bit_cast(unsigned, x);
  unsigned rh = (u + 0x7fffu + ((u >> 16) & 1u)) & 0xffff0000u;
  hi = rh >> 16;
  float res = x - __builtin_bit_cast(float, rh);
  lo = __builtin_bit_cast(unsigned, res) >> 16;
}
__device__ __forceinline__ unsigned pkhl(float x) {
  unsigned u = __builtin_bit_cast(unsigned, x);
  unsigned rh = (u + 0x7fffu + ((u >> 16) & 1u)) & 0xffff0000u;
  float res = x - __builtin_bit_cast(float, rh);
  return (rh >> 16) | (__builtin_bit_cast(unsigned, res) & 0xffff0000u);
}
__device__ __forceinline__ void bsplit(float x, short& hi, short& lo) {
  unsigned p = pkhl(x);
  hi = (short)(p & 0xffff);
  lo = (short)(p >> 16);
}
__device__ __forceinline__ short8 exhi(uint4 q0, uint4 q1) {
  union { unsigned u[4]; short8 s; } r;
  r.u[0] = __builtin_amdgcn_perm(q0.y, q0.x, 0x05040100u);
  r.u[1] = __builtin_amdgcn_perm(q0.w, q0.z, 0x05040100u);
  r.u[2] = __builtin_amdgcn_perm(q1.y, q1.x, 0x05040100u);
  r.u[3] = __builtin_amdgcn_perm(q1.w, q1.z, 0x05040100u);
  return r.s;
}
__device__ __forceinline__ short8 exlo(uint4 q0, uint4 q1) {
  union { unsigned u[4]; short8 s; } r;
  r.u[0] = __builtin_amdgcn_perm(q0.y, q0.x, 0x07060302u);
  r.u[1] = __builtin_amdgcn_perm(q0.w, q0.z, 0x07060302u);
  r.u[2] = __builtin_amdgcn_perm(q1.y, q1.x, 0x07060302u);
  r.u[3] = __builtin_amdgcn_perm(q1.w, q1.z, 0x07060302u);
  return r.s;
}
// D = A*B + C for 16x16x16 bf16 (K=16; A,B = 4 bf16 / lane)
__device__ __forceinline__ f32x4 mfma16(s4b a, s4b b, f32x4 c) {
#if __has_builtin(__builtin_amdgcn_mfma_f32_16x16x16bf16_1k)
  return __builtin_amdgcn_mfma_f32_16x16x16bf16_1k(a, b, c, 0, 0, 0);
#else
  f32x4 d;
  asm("v_mfma_f32_16x16x16_bf16 %0, %1, %2, %3" : "=v"(d) : "v"(a), "v"(b), "v"(c));
  return d;
#endif
}

__global__ void p0(const float* __restrict__ omega, short* __restrict__ wT) {
  int i = blockIdx.x * 256 + threadIdx.x;
  if (i < 4096) {
    int m = i >> 6, d = i & 63;
    short hi, lo;
    bsplit(omega[d * 64 + m], hi, lo);
    wT[m * 64 + d] = hi;
    wT[4096 + m * 64 + d] = lo;
  }
}

// ---------------- Phase 1: per-wave partials of B1[m][c], den[m]. No LDS.
__global__ __launch_bounds__(256, 2) void p1(
    const float* __restrict__ Kg, const float* __restrict__ Vg,
    const short* __restrict__ wT, float* __restrict__ part) {
  const int t = threadIdx.x;
  const int lane = t & 63;
  const int w = t >> 6;
  const int a = lane & 15;
  const int g = lane >> 4;
  const int wid = blockIdx.x * 4 + w;   // 0..2047
  const int bh = wid >> 5;              // head
  const int ci = wid & 31;              // chunk in head
  const float* Kb = Kg + ((size_t)bh * Sc + (size_t)ci * CROWS) * Dc;
  const float* Vb = Vg + ((size_t)bh * Sc + (size_t)ci * CROWS) * Dc;

  // omega B-frags (16x16x32): lane holds w[d=32ks+8g+j][m=16mt+a]
  short8 wfh[4][2], wfl[4][2];
#pragma unroll
  for (int mt = 0; mt < 4; ++mt)
#pragma unroll
    for (int ks = 0; ks < 2; ++ks) {
      int off = (16 * mt + a) * 64 + 32 * ks + 8 * g;
      wfh[mt][ks] = *(const short8*)(wT + off);
      wfl[mt][ks] = *(const short8*)(wT + 4096 + off);
    }

  f32x4 acc[4][4];
#pragma unroll
  for (int mt = 0; mt < 4; ++mt)
#pragma unroll
    for (int ct = 0; ct < 4; ++ct) acc[mt][ct] = (f32x4){0.f, 0.f, 0.f, 0.f};
  float den[4] = {0.f, 0.f, 0.f, 0.f};

  float4 kf[4];  // K[sb+a][8g..8g+7 | 32+8g..32+8g+7]  (A-frag f32)
  float vf[16];  // V[sb+4g+j][16ct+a]                   (B-frag f32)
  auto loadK = [&](int sl) {
    const float* kb = Kb + ((size_t)sl * 16 + a) * 64 + 8 * g;
    kf[0] = *(const float4*)(kb);
    kf[1] = *(const float4*)(kb + 4);
    kf[2] = *(const float4*)(kb + 32);
    kf[3] = *(const float4*)(kb + 36);
  };
  auto loadV = [&](int sl) {
    const float* vb = Vb + ((size_t)sl * 16 + 4 * g) * 64 + a;
#pragma unroll
    for (int ct = 0; ct < 4; ++ct)
#pragma unroll
      for (int j = 0; j < 4; ++j) vf[ct * 4 + j] = vb[j * 64 + 16 * ct];
  };

  loadK(0);
  loadV(0);

  for (int sl = 0; sl < SLABS; ++sl) {
    // row sum-of-squares for row sb+a (this lane's A-frag row)
    float ps = kf[0].x * kf[0].x + kf[0].y * kf[0].y + kf[0].z * kf[0].z + kf[0].w * kf[0].w;
    ps += kf[1].x * kf[1].x + kf[1].y * kf[1].y + kf[1].z * kf[1].z + kf[1].w * kf[1].w;
    ps += kf[2].x * kf[2].x + kf[2].y * kf[2].y + kf[2].z * kf[2].z + kf[2].w * kf[2].w;
    ps += kf[3].x * kf[3].x + kf[3].y * kf[3].y + kf[3].z * kf[3].z + kf[3].w * kf[3].w;
    ps += __shfl_xor(ps, 16, 64);
    ps += __shfl_xor(ps, 32, 64);  // all 4 g-lanes hold ssq[sb+a]

    // split K to bf16 hi/lo A-frags
    short8 ah[2], al[2];
#pragma unroll
    for (int ks = 0; ks < 2; ++ks) {
      float v[8] = {kf[2 * ks].x, kf[2 * ks].y, kf[2 * ks].z, kf[2 * ks].w,
                    kf[2 * ks + 1].x, kf[2 * ks + 1].y, kf[2 * ks + 1].z, kf[2 * ks + 1].w};
#pragma unroll
      for (int i = 0; i < 8; ++i) {
        unsigned h, l;
        bsplitu(v[i], h, l);
        ah[ks][i] = (short)h;
        al[ks][i] = (short)l;
      }
    }
    if (sl + 1 < SLABS) loadK(sl + 1);  // kf dead; prefetch in flight

    // GEMM1: X[s][m] = K @ w  (3-product bf16x2 split, f32 acc)
    f32x4 X[4];
#pragma unroll
    for (int mt = 0; mt < 4; ++mt) X[mt] = (f32x4){0.f, 0.f, 0.f, 0.f};
#pragma unroll
    for (int ks = 0; ks < 2; ++ks)
#pragma unroll
      for (int mt = 0; mt < 4; ++mt) {
        X[mt] = __builtin_amdgcn_mfma_f32_16x16x32_bf16(ah[ks], wfh[mt][ks], X[mt], 0, 0, 0);
        X[mt] = __builtin_amdgcn_mfma_f32_16x16x32_bf16(ah[ks], wfl[mt][ks], X[mt], 0, 0, 0);
        X[mt] = __builtin_amdgcn_mfma_f32_16x16x32_bf16(al[ks], wfh[mt][ks], X[mt], 0, 0, 0);
      }

    // redistribute ssq to D-frag rows: need ssq[s=4g+r] -> src lane 16g+(4g+r)
    float sq[4];
#pragma unroll
    for (int r = 0; r < 4; ++r) sq[r] = __shfl(ps, 20 * g + r, 64);

    // exp -> P (f32 den; bf16 A-frag for GEMM2, chained in-register)
    s4b PA[4];
#pragma unroll
    for (int mt = 0; mt < 4; ++mt) {
#pragma unroll
      for (int r = 0; r < 4; ++r) {
        float p_ = 0.125f * __expf(X[mt][r] - 0.5f * sq[r]);
        den[mt] += p_;
        PA[mt][r] = (short)bf16rtne(p_);
      }
    }

    // V B-frag pack (vf dead after), then prefetch next V
    s4b VB[4];
#pragma unroll
    for (int ct = 0; ct < 4; ++ct)
#pragma unroll
      for (int j = 0; j < 4; ++j) VB[ct][j] = (short)bf16rtne(vf[ct * 4 + j]);
    if (sl + 1 < SLABS) loadV(sl + 1);

    // GEMM2: B1[m][c] += P^T @ V  (16 x mfma 16x16x16)
#pragma unroll
    for (int mt = 0; mt < 4; ++mt)
#pragma unroll
      for (int ct = 0; ct < 4; ++ct) acc[mt][ct] = mfma16(PA[mt], VB[ct], acc[mt][ct]);
  }

  // epilogue: plain partial stores (no atomics)
  float* pp = part + (size_t)wid * PSTRIDE;
#pragma unroll
  for (int mt = 0; mt < 4; ++mt)
#pragma unroll
    for (int ct = 0; ct < 4; ++ct)
#pragma unroll
      for (int r = 0; r < 4; ++r)
        pp[(16 * mt + 4 * g + r) * 64 + 16 * ct + a] = acc[mt][ct][r];
#pragma unroll
  for (int mt = 0; mt < 4; ++mt) {
    float v = den[mt];
    v += __shfl_xor(v, 16, 64);
    v += __shfl_xor(v, 32, 64);
    if (g == 0) pp[4096 + 16 * mt + a] = v;
  }
}

// ---------------- p1r: reduce NCH1 partials -> b1, den
__global__ __launch_bounds__(256) void p1r(
    const float* __restrict__ part, float* __restrict__ b1,
    float* __restrict__ den) {
  int o = blockIdx.x * 256 + threadIdx.x;
  if (o >= NH * PSTRIDE) return;
  int bh = o / PSTRIDE, i = o % PSTRIDE;
  const float* p = part + (size_t)bh * NCH1 * PSTRIDE + i;
  float s = 0.f;
#pragma unroll
  for (int c = 0; c < NCH1; ++c) s += p[(size_t)c * PSTRIDE];
  if (i < 4096) b1[bh * 4096 + i] = s;
  else den[bh * 64 + (i - 4096)] = s;
}

// ---------------- Phase 2 (unchanged — at HBM roofline)
__global__ __launch_bounds__(256, 2) void p2(
    const float* __restrict__ Qg, const short* __restrict__ wT,
    const float* __restrict__ b1, const float* __restrict__ den,
    float* __restrict__ out) {
  __shared__ unsigned Qpk[64 * 68];
  __shared__ unsigned QP[64 * 68];
  __shared__ short B1h[64 * 72], B1l[64 * 72];
  __shared__ float denv[64];
  __shared__ float ssq[64];

  const int t = threadIdx.x;
  const int lane = t & 63;
  const int w = t >> 6;
  const int a = lane & 15;
  const int g = lane >> 4;
  const int bh = blockIdx.x / NCHUNK2, ch = blockIdx.x % NCHUNK2;
  const float* Qb = Qg + ((size_t)bh * Sc + (size_t)ch * CH2) * Dc;

  short8 wfh[4][2], wfl[4][2];
#pragma unroll
  for (int mt = 0; mt < 4; ++mt)
#pragma unroll
    for (int ks = 0; ks < 2; ++ks) {
      int off = (a + 16 * mt) * 64 + 32 * ks + 8 * g;
      wfh[mt][ks] = *(const short8*)(wT + off);
      wfl[mt][ks] = *(const short8*)(wT + 4096 + off);
    }

  const float* b1g = b1 + (size_t)bh * 4096;
  for (int i = t; i < 4096; i += 256) {
    int m = i >> 6, c = i & 63;
    short hi, lo;
    bsplit(b1g[i], hi, lo);
    B1h[c * 72 + m] = hi;
    B1l[c * 72 + m] = lo;
  }
  if (t < 64) denv[t] = den[bh * 64 + t];

  float4 qreg[4];
  auto load_tile = [&](int tile) {
    const float4* Qt = (const float4*)(Qb + (size_t)tile * 64 * Dc);
#pragma unroll
    for (int rr = 0; rr < 4; ++rr) qreg[rr] = Qt[rr * 256 + t];
  };
  auto store_tile = [&]() {
#pragma unroll
    for (int rr = 0; rr < 4; ++rr) {
      int idx = rr * 256 + t;
      int row = idx >> 4;
      int c4 = idx & 15;
      float4 kv = qreg[rr];
      uint4 qp;
      qp.x = pkhl(kv.x); qp.y = pkhl(kv.y);
      qp.z = pkhl(kv.z); qp.w = pkhl(kv.w);
      *(uint4*)&Qpk[row * 68 + 4 * c4] = qp;
      float ps = kv.x * kv.x + kv.y * kv.y + kv.z * kv.z + kv.w * kv.w;
      ps += __shfl_xor(ps, 1, 64); ps += __shfl_xor(ps, 2, 64);
      ps += __shfl_xor(ps, 4, 64); ps += __shfl_xor(ps, 8, 64);
      if (c4 == 0) ssq[row] = ps;
    }
  };

  load_tile(0);
  store_tile();
  __syncthreads();

  for (int tile = 0; tile < TPT2; ++tile) {
    if (tile + 1 < TPT2) load_tile(tile + 1);

    f32x4 X[4];
#pragma unroll
    for (int mt = 0; mt < 4; ++mt) X[mt] = (f32x4){0.f, 0.f, 0.f, 0.f};
#pragma unroll
    for (int ks = 0; ks < 2; ++ks) {
      const unsigned* qb = &Qpk[(16 * w + a) * 68 + 32 * ks + 8 * g];
      uint4 q0 = *(const uint4*)qb;
      uint4 q1 = *(const uint4*)(qb + 4);
      short8 ah = exhi(q0, q1), al = exlo(q0, q1);
#pragma unroll
      for (int mt = 0; mt < 4; ++mt) {
        X[mt] = __builtin_amdgcn_mfma_f32_16x16x32_bf16(ah, wfh[mt][ks], X[mt], 0, 0, 0);
        X[mt] = __builtin_amdgcn_mfma_f32_16x16x32_bf16(ah, wfl[mt][ks], X[mt], 0, 0, 0);
        X[mt] = __builtin_amdgcn_mfma_f32_16x16x32_bf16(al, wfh[mt][ks], X[mt], 0, 0, 0);
      }
    }

    float sq[4];
#pragma unroll
    for (int r = 0; r < 4; ++r) sq[r] = ssq[16 * w + 4 * g + r];
    float dv[4];
#pragma unroll
    for (int mt = 0; mt < 4; ++mt) dv[mt] = denv[16 * mt + a];
    float dn[4] = {0.f, 0.f, 0.f, 0.f};
#pragma unroll
    for (int mt = 0; mt < 4; ++mt) {
#pragma unroll
      for (int r = 0; r < 4; ++r) {
        float p_ = 0.125f * __expf(X[mt][r] - 0.5f * sq[r]);
        dn[r] = fmaf(p_, dv[mt], dn[r]);
        QP[(16 * w + 4 * g + r) * 68 + 16 * mt + a] = pkhl(p_);
      }
    }
#pragma unroll
    for (int r = 0; r < 4; ++r) {
      dn[r] += __shfl_xor(dn[r], 1, 64);
      dn[r] += __shfl_xor(dn[r], 2, 64);
      dn[r] += __shfl_xor(dn[r], 4, 64);
      dn[r] += __shfl_xor(dn[r], 8, 64);
    }
    __syncthreads();  // A

    f32x4 O[4];
#pragma unroll
    for (int ct = 0; ct < 4; ++ct) O[ct] = (f32x4){0.f, 0.f, 0.f, 0.f};
#pragma unroll
    for (int ks = 0; ks < 2; ++ks) {
      const unsigned* qb = &QP[(16 * w + a) * 68 + 32 * ks + 8 * g];
      uint4 r0 = *(const uint4*)qb;
      uint4 r1 = *(const uint4*)(qb + 4);
      short8 qh = exhi(r0, r1), ql = exlo(r0, r1);
#pragma unroll
      for (int ct = 0; ct < 4; ++ct) {
        short8 bh_ = *(const short8*)&B1h[(16 * ct + a) * 72 + 32 * ks + 8 * g];
        short8 bl_ = *(const short8*)&B1l[(16 * ct + a) * 72 + 32 * ks + 8 * g];
        O[ct] = __builtin_amdgcn_mfma_f32_16x16x32_bf16(qh, bh_, O[ct], 0, 0, 0);
        O[ct] = __builtin_amdgcn_mfma_f32_16x16x32_bf16(qh, bl_, O[ct], 0, 0, 0);
        O[ct] = __builtin_amdgcn_mfma_f32_16x16x32_bf16(ql, bh_, O[ct], 0, 0, 0);
      }
    }

    float inv[4];
#pragma unroll
    for (int r = 0; r < 4; ++r) inv[r] = 1.0f / dn[r];
    float* ob = out + ((size_t)bh * Sc + (size_t)ch * CH2 + tile * 64 + 16 * w + 4 * g) * 64;
#pragma unroll
    for (int ct = 0; ct < 4; ++ct)
#pragma unroll
      for (int r = 0; r < 4; ++r)
        ob[r * 64 + 16 * ct + a] = O[ct][r] * inv[r];
    __syncthreads();  // B
    if (tile + 1 < TPT2) store_tile();
    __syncthreads();  // C
  }
}

extern "C" void kernel_launch(void* const* d_in, const int* in_sizes, int n_in,
                              void* d_out, int out_size, void* d_ws, size_t ws_size,
                              hipStream_t stream) {
  const float* Q = (const float*)d_in[0];
  const float* K = (const float*)d_in[1];
  const float* V = (const float*)d_in[2];
  const float* omega = (const float*)d_in[3];
  float* outp = (float*)d_out;
  float* part = (float*)d_out;                 // 2048*4160*4B = 34 MB << 128 MB
  float* b1 = (float*)d_ws;                    // 64*4096 floats
  float* den = b1 + (size_t)NH * 4096;         // 64*64 floats
  short* wT = (short*)(den + NH * 64);         // 8192 shorts

  p0<<<16, 256, 0, stream>>>(omega, wT);
  p1<<<NH * NCH1 / 4, 256, 0, stream>>>(K, V, wT, part);  // 512 blocks, 2048 waves
  p1r<<<(NH * PSTRIDE + 255) / 256, 256, 0, stream>>>(part, b1, den);
  p2<<<NH * NCHUNK2, 256, 0, stream>>>(Q, wT, b1, den, outp);
}